// Round 3
// baseline (268.772 us; speedup 1.0000x reference)
//
#include <hip/hip_runtime.h>
#include <hip/hip_bf16.h>
#include <math.h>

// Problem constants
#define BB   2
#define CIN  32
#define COUT 32
#define DM   40
#define PD   42                 // padded spatial dim
#define NPTS (DM*DM)            // 1600
#define NVOL (DM*DM*DM)         // 64000
#define EPSBN 1e-5f

typedef short  bf16x8  __attribute__((ext_vector_type(8)));
typedef float  floatx4 __attribute__((ext_vector_type(4)));

// Workspace layout (float offsets), all 16B-aligned
#define WS_WFRAG 0              // bf16[55296] = 27648 floats
#define WS_BCOMB 27648          // 64 floats
#define WS_SUM   27712          // 64 floats: sum[32], sumsq[32]
#define WS_XPAD2 27776          // bf16[2*42^3*32] = 2370816 floats
#define WS_Y     2398592        // 2*32*64000 = 4096000 floats
// total ~6.5M floats = 26 MB

#define REPACK_BLOCKS (PD*PD*BB)          // 3528
#define PREP_ELEMS    (55296 + 64 + 64)   // wfrag + bias + zero-sums
#define PREP_BLOCKS   ((PREP_ELEMS + 255) / 256)   // 217

// ---------------------------------------------------------------------------
// Kernel 1: fused prep (routing + B-fragment weights + bias + zero stats)
//           and channels-last zero-padded bf16 repack of x.
// wfrag[b][ntile][tap][lane][j] = W_b[i=(lane>>4)*8+j][o=ntile*16+(lane&15)][tap]
// ---------------------------------------------------------------------------
__global__ void prep_repack_kernel(const float* __restrict__ x,
                                   const float* __restrict__ emb,
                                   const float* __restrict__ rw,
                                   const float* __restrict__ rb,
                                   const float* __restrict__ ek,
                                   const float* __restrict__ ebias,
                                   float* __restrict__ ws) {
    const int bid = blockIdx.x;
    if (bid < REPACK_BLOCKS) {
        // ---- repack role ----
        int b  = bid / (PD * PD);
        int r  = bid % (PD * PD);
        int zp = r / PD, yp = r % PD;
        __hip_bfloat16* row = (__hip_bfloat16*)(ws + WS_XPAD2) +
                              ((((size_t)b * PD + zp) * PD + yp) * PD) * 32;
        bool inz = (zp >= 1 && zp <= DM && yp >= 1 && yp <= DM);
        for (int idx = threadIdx.x; idx < PD * 32; idx += 256) {
            int i = idx & 31, xp = idx >> 5;
            float v = 0.0f;
            if (inz && xp >= 1 && xp <= DM)
                v = x[(size_t)(b * CIN + i) * NVOL +
                      (zp - 1) * NPTS + (yp - 1) * DM + (xp - 1)];
            row[idx] = __float2bfloat16(v);
        }
        return;
    }
    // ---- prep role ----
    int idx = (bid - REPACK_BLOCKS) * 256 + threadIdx.x;
    __hip_bfloat16* wfrag = (__hip_bfloat16*)(ws + WS_WFRAG);
    const int NW = 2 * 2 * 27 * 64 * 8;   // 55296
    if (idx < NW) {
        int j    = idx & 7;
        int lane = (idx >> 3) & 63;
        int tap  = (idx >> 9) % 27;
        int nt   = (idx / (27 * 512)) & 1;
        int b    = idx / (2 * 27 * 512);
        int o = nt * 16 + (lane & 15);
        int i = (lane >> 4) * 8 + j;
        float e0 = emb[b];
        float w = 0.0f;
        #pragma unroll
        for (int e = 0; e < 3; ++e) {
            float r = 1.0f / (1.0f + expf(-(e0 * rw[e] + rb[e])));
            w += r * ek[((e * COUT + o) * CIN + i) * 27 + tap];
        }
        wfrag[idx] = __float2bfloat16(w);
    } else if (idx < NW + 64) {
        int j2 = idx - NW;
        int b = j2 >> 5, o = j2 & 31;
        float e0 = emb[b];
        float bv = 0.0f;
        #pragma unroll
        for (int e = 0; e < 3; ++e) {
            float r = 1.0f / (1.0f + expf(-(e0 * rw[e] + rb[e])));
            bv += r * ebias[e * COUT + o];
        }
        ws[WS_BCOMB + j2] = bv;
    } else if (idx < NW + 128) {
        ws[WS_SUM + (idx - NW - 64)] = 0.0f;   // zero sum[32]+sumsq[32]
    }
}

// ---------------------------------------------------------------------------
// Kernel 2: implicit-GEMM conv via MFMA bf16 + fused batch-stat accumulation
// grid (mc=50, z=40, b=2), block 256 = 4 waves
// wave w: mtile = w&1 (16 spatial pts), ntile = w>>1 (16 out chans)
// ---------------------------------------------------------------------------
__global__ __launch_bounds__(256) void conv_mfma_kernel(
        const __hip_bfloat16* __restrict__ xp2,
        const bf16x8* __restrict__ wfrag,
        const float* __restrict__ bcomb,
        float* __restrict__ y,
        float* __restrict__ sums) {
    const int mc = blockIdx.x, z = blockIdx.y, b = blockIdx.z;
    const int tid = threadIdx.x, lane = tid & 63, wv = tid >> 6;
    const int mt = wv & 1, nt = wv >> 1;
    const int quad = lane >> 4, l15 = lane & 15;

    __shared__ float lstat[64];
    if (tid < 64) lstat[tid] = 0.0f;
    __syncthreads();

    // A fragment: lane's spatial point = row of A; quad selects channel group
    const int pa = mc * 32 + mt * 16 + l15;     // 0..1599 within plane z
    const int ya = pa / DM, xa = pa % DM;
    const char* abase = (const char*)xp2 +
        ((((size_t)b * PD + z) * PD + ya) * PD + xa) * 64 + quad * 16;
    // B fragments: pre-shuffled, lane-indexed
    const bf16x8* wbase = wfrag + ((b * 2 + nt) * 27) * 64 + lane;

    floatx4 acc0 = {0.f, 0.f, 0.f, 0.f};
    floatx4 acc1 = {0.f, 0.f, 0.f, 0.f};
    #pragma unroll
    for (int t = 0; t < 27; ++t) {
        const int dz = t / 9, dy = (t / 3) % 3, dx = t % 3;
        bf16x8 av = *(const bf16x8*)(abase + ((dz * PD + dy) * PD + dx) * 64);
        bf16x8 bv = wbase[t * 64];
        if (t & 1) acc1 = __builtin_amdgcn_mfma_f32_16x16x32_bf16(av, bv, acc1, 0, 0, 0);
        else       acc0 = __builtin_amdgcn_mfma_f32_16x16x32_bf16(av, bv, acc0, 0, 0, 0);
    }
    floatx4 acc = acc0 + acc1;

    // Epilogue: D[m=quad*4+reg][n=l15]; lane's 4 values share out-channel o
    const int o = nt * 16 + l15;
    const float bias = bcomb[b * COUT + o];
    const int po = mc * 32 + mt * 16 + quad * 4;
    float v0 = acc[0] + bias;
    float v1 = acc[1] + bias;
    float v2 = acc[2] + bias;
    float v3 = acc[3] + bias;
    *(float4*)(y + ((size_t)(b * COUT + o) * DM + z) * NPTS + po) =
        make_float4(v0, v1, v2, v3);

    // Wave-level stat reduce: lanes l, l+16, l+32, l+48 share o
    float vs = v0 + v1 + v2 + v3;
    float vq = v0 * v0 + v1 * v1 + v2 * v2 + v3 * v3;
    vs += __shfl_xor(vs, 16); vq += __shfl_xor(vq, 16);
    vs += __shfl_xor(vs, 32); vq += __shfl_xor(vq, 32);
    if (lane < 16) {
        atomicAdd(&lstat[o],      vs);
        atomicAdd(&lstat[32 + o], vq);
    }
    __syncthreads();
    if (tid < 64) atomicAdd(&sums[tid], lstat[tid]);   // device-scope, 64 addrs
}

// ---------------------------------------------------------------------------
// Kernel 3: BN params from sums + BN apply + LeakyReLU + upsample x2
// 2 source voxels per thread; 4x float4 stores. grid 8000 x 256.
// ---------------------------------------------------------------------------
__global__ void upsample_kernel(const float* __restrict__ yin,
                                const float* __restrict__ sums,
                                const float* __restrict__ gamma,
                                const float* __restrict__ beta,
                                float* __restrict__ out) {
    __shared__ float ssc[32], ssh[32];
    const int tid = threadIdx.x;
    if (tid < 32) {
        const float invN = 1.0f / (float)(BB * NVOL);
        float mean  = sums[tid] * invN;
        float var   = sums[32 + tid] * invN - mean * mean;
        float scale = gamma[tid] * rsqrtf(var + EPSBN);
        ssc[tid] = scale;
        ssh[tid] = beta[tid] - mean * scale;
    }
    __syncthreads();

    int idx = blockIdx.x * 256 + tid;        // 0 .. 2,048,000
    int cc = idx / (NVOL / 2);               // b*COUT + c
    int p  = idx % (NVOL / 2);
    int z  = p / (NPTS / 2);
    int yy = (p / (DM / 2)) % DM;
    int x2 = p % (DM / 2);                   // pair index: src x = 2*x2, 2*x2+1
    int c  = cc & 31;

    float2 v = *(const float2*)(yin + (size_t)idx * 2);
    float sc = ssc[c], sh = ssh[c];
    float w0 = v.x * sc + sh; w0 = (w0 >= 0.0f) ? w0 : 0.1f * w0;
    float w1 = v.y * sc + sh; w1 = (w1 >= 0.0f) ? w1 : 0.1f * w1;

    float4 q = make_float4(w0, w0, w1, w1);
    size_t obase = ((size_t)cc * 80 + (size_t)(2 * z)) * 6400
                 + (size_t)(2 * yy) * 80 + (size_t)(4 * x2);
    *(float4*)(out + obase)        = q;
    *(float4*)(out + obase + 80)   = q;
    *(float4*)(out + obase + 6400) = q;
    *(float4*)(out + obase + 6480) = q;
}

// ---------------------------------------------------------------------------
extern "C" void kernel_launch(void* const* d_in, const int* in_sizes, int n_in,
                              void* d_out, int out_size, void* d_ws, size_t ws_size,
                              hipStream_t stream) {
    const float* x     = (const float*)d_in[0];
    const float* emb   = (const float*)d_in[1];
    const float* rw    = (const float*)d_in[2];
    const float* rb    = (const float*)d_in[3];
    const float* ek    = (const float*)d_in[4];
    const float* ebias = (const float*)d_in[5];
    const float* gamma = (const float*)d_in[6];
    const float* beta  = (const float*)d_in[7];
    float* ws  = (float*)d_ws;
    float* out = (float*)d_out;

    // 1: prep + repack (+ zero stat accumulators)
    prep_repack_kernel<<<REPACK_BLOCKS + PREP_BLOCKS, 256, 0, stream>>>(
        x, emb, rw, rb, ek, ebias, ws);

    // 2: MFMA conv + stats
    conv_mfma_kernel<<<dim3(50, DM, BB), 256, 0, stream>>>(
        (const __hip_bfloat16*)(ws + WS_XPAD2), (const bf16x8*)(ws + WS_WFRAG),
        ws + WS_BCOMB, ws + WS_Y, ws + WS_SUM);

    // 3: BN params + apply + LeakyReLU + upsample
    upsample_kernel<<<(BB * COUT * NVOL / 2) / 256, 256, 0, stream>>>(
        ws + WS_Y, ws + WS_SUM, gamma, beta, out);
}

// Round 4
// 205.970 us; speedup vs baseline: 1.3049x; 1.3049x over previous
//
#include <hip/hip_runtime.h>
#include <hip/hip_bf16.h>
#include <math.h>

// Problem constants
#define BB   2
#define CIN  32
#define COUT 32
#define DM   40
#define PD   42                 // padded spatial dim
#define NPTS (DM*DM)            // 1600
#define NVOL (DM*DM*DM)         // 64000
#define EPSBN 1e-5f
#define NSLOT 64                // stat-accumulator slots (spread atomics)

typedef short  bf16x8  __attribute__((ext_vector_type(8)));
typedef float  floatx4 __attribute__((ext_vector_type(4)));

// Workspace layout (float offsets), all 16B-aligned
#define WS_WFRAG 0              // bf16[55296] = 27648 floats
#define WS_BCOMB 27648          // 64 floats
#define WS_SUM2  27712          // 64 slots * 64 stats = 4096 floats
#define WS_XPAD2 31808          // bf16[2*42^3*32] = 2370816 floats
#define WS_Y     2402624        // 2*32*64000 = 4096000 floats

#define REPACK_BLOCKS (PD*PD*BB)                  // 3528
#define NW_ELEMS  (2*2*27*64*8)                   // 55296
#define PREP_ELEMS (NW_ELEMS + 64 + NSLOT*64)     // wfrag + bias + zero sums2
#define PREP_BLOCKS ((PREP_ELEMS + 255) / 256)    // 233

// ---------------------------------------------------------------------------
// Kernel 1: fused prep (routing + B-fragment weights + bias + zero stat slots)
//           and channels-last zero-padded bf16 repack of x.
// wfrag[b][ntile][tap][lane][j] = W_b[i=(lane>>4)*8+j][o=ntile*16+(lane&15)][tap]
// ---------------------------------------------------------------------------
__global__ void prep_repack_kernel(const float* __restrict__ x,
                                   const float* __restrict__ emb,
                                   const float* __restrict__ rw,
                                   const float* __restrict__ rb,
                                   const float* __restrict__ ek,
                                   const float* __restrict__ ebias,
                                   float* __restrict__ ws) {
    const int bid = blockIdx.x;
    if (bid < REPACK_BLOCKS) {
        // ---- repack role ----
        int b  = bid / (PD * PD);
        int r  = bid % (PD * PD);
        int zp = r / PD, yp = r % PD;
        __hip_bfloat16* row = (__hip_bfloat16*)(ws + WS_XPAD2) +
                              ((((size_t)b * PD + zp) * PD + yp) * PD) * 32;
        bool inz = (zp >= 1 && zp <= DM && yp >= 1 && yp <= DM);
        for (int idx = threadIdx.x; idx < PD * 32; idx += 256) {
            int i = idx & 31, xp = idx >> 5;
            float v = 0.0f;
            if (inz && xp >= 1 && xp <= DM)
                v = x[(size_t)(b * CIN + i) * NVOL +
                      (zp - 1) * NPTS + (yp - 1) * DM + (xp - 1)];
            row[idx] = __float2bfloat16(v);
        }
        return;
    }
    // ---- prep role ----
    int idx = (bid - REPACK_BLOCKS) * 256 + threadIdx.x;
    __hip_bfloat16* wfrag = (__hip_bfloat16*)(ws + WS_WFRAG);
    if (idx < NW_ELEMS) {
        int j    = idx & 7;
        int lane = (idx >> 3) & 63;
        int tap  = (idx >> 9) % 27;
        int nt   = (idx / (27 * 512)) & 1;
        int b    = idx / (2 * 27 * 512);
        int o = nt * 16 + (lane & 15);
        int i = (lane >> 4) * 8 + j;
        float e0 = emb[b];
        float w = 0.0f;
        #pragma unroll
        for (int e = 0; e < 3; ++e) {
            float r = 1.0f / (1.0f + expf(-(e0 * rw[e] + rb[e])));
            w += r * ek[((e * COUT + o) * CIN + i) * 27 + tap];
        }
        wfrag[idx] = __float2bfloat16(w);
    } else if (idx < NW_ELEMS + 64) {
        int j2 = idx - NW_ELEMS;
        int b = j2 >> 5, o = j2 & 31;
        float e0 = emb[b];
        float bv = 0.0f;
        #pragma unroll
        for (int e = 0; e < 3; ++e) {
            float r = 1.0f / (1.0f + expf(-(e0 * rw[e] + rb[e])));
            bv += r * ebias[e * COUT + o];
        }
        ws[WS_BCOMB + j2] = bv;
    } else if (idx < PREP_ELEMS) {
        ws[WS_SUM2 + (idx - NW_ELEMS - 64)] = 0.0f;   // zero sums2[64][64]
    }
}

// ---------------------------------------------------------------------------
// Kernel 2: implicit-GEMM conv via MFMA bf16 + slot-spread batch-stat atomics
// grid (mc=50, z=40, b=2), block 256 = 4 waves
// wave w: mtile = w&1 (16 spatial pts), ntile = w>>1 (16 out chans)
// ---------------------------------------------------------------------------
__global__ __launch_bounds__(256, 4) void conv_mfma_kernel(
        const __hip_bfloat16* __restrict__ xp2,
        const bf16x8* __restrict__ wfrag,
        const float* __restrict__ bcomb,
        float* __restrict__ y,
        float* __restrict__ sums2) {
    const int mc = blockIdx.x, z = blockIdx.y, b = blockIdx.z;
    const int tid = threadIdx.x, lane = tid & 63, wv = tid >> 6;
    const int mt = wv & 1, nt = wv >> 1;
    const int quad = lane >> 4, l15 = lane & 15;

    __shared__ float lstat[64];
    if (tid < 64) lstat[tid] = 0.0f;
    __syncthreads();

    // A fragment: lane's spatial point = row of A; quad selects channel group
    const int pa = mc * 32 + mt * 16 + l15;     // 0..1599 within plane z
    const int ya = pa / DM, xa = pa % DM;
    const char* abase = (const char*)xp2 +
        ((((size_t)b * PD + z) * PD + ya) * PD + xa) * 64 + quad * 16;
    // B fragments: pre-shuffled, lane-indexed
    const bf16x8* wbase = wfrag + ((b * 2 + nt) * 27) * 64 + lane;

    floatx4 acc0 = {0.f, 0.f, 0.f, 0.f};
    floatx4 acc1 = {0.f, 0.f, 0.f, 0.f};
    #pragma unroll
    for (int t = 0; t < 27; ++t) {
        const int dz = t / 9, dy = (t / 3) % 3, dx = t % 3;
        bf16x8 av = *(const bf16x8*)(abase + ((dz * PD + dy) * PD + dx) * 64);
        bf16x8 bv = wbase[t * 64];
        if (t & 1) acc1 = __builtin_amdgcn_mfma_f32_16x16x32_bf16(av, bv, acc1, 0, 0, 0);
        else       acc0 = __builtin_amdgcn_mfma_f32_16x16x32_bf16(av, bv, acc0, 0, 0, 0);
    }
    floatx4 acc = acc0 + acc1;

    // Epilogue: D[m=quad*4+reg][n=l15]; lane's 4 values share out-channel o
    const int o = nt * 16 + l15;
    const float bias = bcomb[b * COUT + o];
    const int po = mc * 32 + mt * 16 + quad * 4;
    float v0 = acc[0] + bias;
    float v1 = acc[1] + bias;
    float v2 = acc[2] + bias;
    float v3 = acc[3] + bias;
    *(float4*)(y + ((size_t)(b * COUT + o) * DM + z) * NPTS + po) =
        make_float4(v0, v1, v2, v3);

    // Wave-level stat reduce: lanes l, l+16, l+32, l+48 share o
    float vs = v0 + v1 + v2 + v3;
    float vq = v0 * v0 + v1 * v1 + v2 * v2 + v3 * v3;
    vs += __shfl_xor(vs, 16); vq += __shfl_xor(vq, 16);
    vs += __shfl_xor(vs, 32); vq += __shfl_xor(vq, 32);
    if (lane < 16) {
        atomicAdd(&lstat[o],      vs);
        atomicAdd(&lstat[32 + o], vq);
    }
    __syncthreads();
    if (tid < 64) {
        int slot = ((b * DM + z) * 50 + mc) & (NSLOT - 1);
        atomicAdd(&sums2[slot * 64 + tid], lstat[tid]);  // spread: 4096 addrs
    }
}

// ---------------------------------------------------------------------------
// Kernel 3: reduce stat slots -> BN params; BN apply + LeakyReLU + upsample x2
// 2 source voxels per thread; 4x float4 stores. grid 8000 x 256.
// ---------------------------------------------------------------------------
__global__ void upsample_kernel(const float* __restrict__ yin,
                                const float* __restrict__ sums2,
                                const float* __restrict__ gamma,
                                const float* __restrict__ beta,
                                float* __restrict__ out) {
    __shared__ float partl[4][64];
    __shared__ float ssc[32], ssh[32];
    const int tid = threadIdx.x;
    {   // 256 threads: group sg reduces 16 slots for stat st
        int sg = tid >> 6, st = tid & 63;
        float p = 0.0f;
        #pragma unroll
        for (int s = 0; s < 16; ++s) p += sums2[(sg * 16 + s) * 64 + st];
        partl[sg][st] = p;
    }
    __syncthreads();
    if (tid < 64) {
        partl[0][tid] += partl[1][tid] + partl[2][tid] + partl[3][tid];
    }
    __syncthreads();
    if (tid < 32) {
        const float invN = 1.0f / (float)(BB * NVOL);
        float mean  = partl[0][tid] * invN;
        float var   = partl[0][32 + tid] * invN - mean * mean;
        float scale = gamma[tid] * rsqrtf(var + EPSBN);
        ssc[tid] = scale;
        ssh[tid] = beta[tid] - mean * scale;
    }
    __syncthreads();

    int idx = blockIdx.x * 256 + tid;        // 0 .. 2,048,000
    int cc = idx / (NVOL / 2);               // b*COUT + c
    int p  = idx % (NVOL / 2);
    int z  = p / (NPTS / 2);
    int yy = (p / (DM / 2)) % DM;
    int x2 = p % (DM / 2);                   // pair index: src x = 2*x2, 2*x2+1
    int c  = cc & 31;

    float2 v = *(const float2*)(yin + (size_t)idx * 2);
    float sc = ssc[c], sh = ssh[c];
    float w0 = v.x * sc + sh; w0 = (w0 >= 0.0f) ? w0 : 0.1f * w0;
    float w1 = v.y * sc + sh; w1 = (w1 >= 0.0f) ? w1 : 0.1f * w1;

    float4 q = make_float4(w0, w0, w1, w1);
    size_t obase = ((size_t)cc * 80 + (size_t)(2 * z)) * 6400
                 + (size_t)(2 * yy) * 80 + (size_t)(4 * x2);
    *(float4*)(out + obase)        = q;
    *(float4*)(out + obase + 80)   = q;
    *(float4*)(out + obase + 6400) = q;
    *(float4*)(out + obase + 6480) = q;
}

// ---------------------------------------------------------------------------
extern "C" void kernel_launch(void* const* d_in, const int* in_sizes, int n_in,
                              void* d_out, int out_size, void* d_ws, size_t ws_size,
                              hipStream_t stream) {
    const float* x     = (const float*)d_in[0];
    const float* emb   = (const float*)d_in[1];
    const float* rw    = (const float*)d_in[2];
    const float* rb    = (const float*)d_in[3];
    const float* ek    = (const float*)d_in[4];
    const float* ebias = (const float*)d_in[5];
    const float* gamma = (const float*)d_in[6];
    const float* beta  = (const float*)d_in[7];
    float* ws  = (float*)d_ws;
    float* out = (float*)d_out;

    // 1: prep + repack (+ zero stat slots)
    prep_repack_kernel<<<REPACK_BLOCKS + PREP_BLOCKS, 256, 0, stream>>>(
        x, emb, rw, rb, ek, ebias, ws);

    // 2: MFMA conv + slot-spread stats
    conv_mfma_kernel<<<dim3(50, DM, BB), 256, 0, stream>>>(
        (const __hip_bfloat16*)(ws + WS_XPAD2), (const bf16x8*)(ws + WS_WFRAG),
        ws + WS_BCOMB, ws + WS_Y, ws + WS_SUM2);

    // 3: reduce slots + BN params + apply + LeakyReLU + upsample
    upsample_kernel<<<(BB * COUT * NVOL / 2) / 256, 256, 0, stream>>>(
        ws + WS_Y, ws + WS_SUM2, gamma, beta, out);
}